// Round 6
// baseline (1300.875 us; speedup 1.0000x reference)
//
#include <hip/hip_runtime.h>

typedef unsigned short u16;
typedef unsigned int u32;
typedef unsigned long long u64;
typedef __attribute__((ext_vector_type(8))) short s16x8;
typedef __attribute__((ext_vector_type(4))) float f32x4;
typedef __attribute__((ext_vector_type(16))) float f32x16;

#define NTOK 4096
#define CAP 144

#define MFMA32(a,b,c) __builtin_amdgcn_mfma_f32_32x32x16_bf16(a,b,c,0,0,0)
#define MFMA16(a,b,c) __builtin_amdgcn_mfma_f32_16x16x32_bf16(a,b,c,0,0,0)

union U16x8 { uint4 u; u16 s[8]; };
union Dw4 { u32 d[4]; s16x8 v; };

__device__ __forceinline__ u16 f2bf(float f) {
    u32 u = __float_as_uint(f);
    u32 r = u + 0x7FFFu + ((u >> 16) & 1u);
    return (u16)(r >> 16);
}
__device__ __forceinline__ u32 pkbf(float lo, float hi) {
    u32 r;
    asm("v_cvt_pk_bf16_f32 %0, %1, %2" : "=v"(r) : "v"(lo), "v"(hi));
    return r;
}
__device__ __forceinline__ void unpack8(uint4 u, float* f) {
    f[0] = __uint_as_float(u.x << 16); f[1] = __uint_as_float(u.x & 0xFFFF0000u);
    f[2] = __uint_as_float(u.y << 16); f[3] = __uint_as_float(u.y & 0xFFFF0000u);
    f[4] = __uint_as_float(u.z << 16); f[5] = __uint_as_float(u.z & 0xFFFF0000u);
    f[6] = __uint_as_float(u.w << 16); f[7] = __uint_as_float(u.w & 0xFFFF0000u);
}
__device__ __forceinline__ u32 mapkey(float f) {
    u32 b = __float_as_uint(f);
    return (b & 0x80000000u) ? ~b : (b | 0x80000000u);
}

// ---------------- row L2-normalize (128-wide rows) -> bf16 rows and/or f32 transposed ----------------
__global__ __launch_bounds__(256) void norm_rows_kernel(const float* __restrict__ in,
                                                        u16* __restrict__ out16,
                                                        float* __restrict__ outT, int rows)
{
    int row = blockIdx.x * 4 + (threadIdx.x >> 6);
    int lane = threadIdx.x & 63;
    if (row >= rows) return;
    float2 v = *(const float2*)&in[(size_t)row * 128 + lane * 2];
    float ss = v.x * v.x + v.y * v.y;
    #pragma unroll
    for (int o = 1; o < 64; o <<= 1) ss += __shfl_xor(ss, o);
    float rn = 1.0f / (sqrtf(ss) + 1e-8f);
    float2 ov = make_float2(v.x * rn, v.y * rn);
    if (out16)
        *(u32*)&out16[(size_t)row * 128 + lane * 2] = pkbf(ov.x, ov.y);
    if (outT) {
        outT[(2 * lane) * 64 + row] = ov.x;
        outT[(2 * lane + 1) * 64 + row] = ov.y;
    }
}

// ---------------- f32 -> bf16 cast ----------------
__global__ __launch_bounds__(256) void cast_bf16_kernel(const float* __restrict__ in,
                                                        u16* __restrict__ out, int n)
{
    int i = (blockIdx.x * 256 + threadIdx.x) * 4;
    if (i >= n) return;
    float4 v = *(const float4*)&in[i];
    ushort4 o;
    o.x = f2bf(v.x); o.y = f2bf(v.y); o.z = f2bf(v.z); o.w = f2bf(v.w);
    *(ushort4*)&out[i] = o;
}

// ---------------- transpose + cast: in f32 [Kk][Nn] -> out bf16 [Nn][Kk] ----------------
__global__ void transpose_cast_kernel(const float* __restrict__ in, u16* __restrict__ out,
                                      int Nn, int Kk)
{
    __shared__ float sT[64][65];
    int n0 = blockIdx.x * 64, k0 = blockIdx.y * 64;
    int tx = threadIdx.x, ty = threadIdx.y;
    #pragma unroll
    for (int r = 0; r < 64; r += 4)
        sT[ty + r][tx] = in[(size_t)(k0 + ty + r) * Nn + n0 + tx];
    __syncthreads();
    #pragma unroll
    for (int r = 0; r < 64; r += 4)
        out[(size_t)(n0 + ty + r) * Kk + k0 + tx] = f2bf(sT[tx][ty + r]);
}

// ---------------- LayerNorm over 1024 dims (+fused bf16 copy), one block per token ----------------
__global__ __launch_bounds__(256) void ln_kernel(const float* __restrict__ x,
                                                 const float* __restrict__ gam,
                                                 const float* __restrict__ bet,
                                                 float* __restrict__ out,
                                                 u16* __restrict__ outbf)
{
    __shared__ float red[8];
    int t = blockIdx.x, tid = threadIdx.x;
    const float* row = x + (size_t)t * 1024;
    float4 v = *(const float4*)&row[tid * 4];
    float s = v.x + v.y + v.z + v.w;
    #pragma unroll
    for (int o = 1; o < 64; o <<= 1) s += __shfl_xor(s, o);
    if ((tid & 63) == 0) red[tid >> 6] = s;
    __syncthreads();
    float mean = (red[0] + red[1] + red[2] + red[3]) * (1.0f / 1024.0f);
    float d0 = v.x - mean, d1 = v.y - mean, d2 = v.z - mean, d3 = v.w - mean;
    float ss = d0 * d0 + d1 * d1 + d2 * d2 + d3 * d3;
    #pragma unroll
    for (int o = 1; o < 64; o <<= 1) ss += __shfl_xor(ss, o);
    if ((tid & 63) == 0) red[4 + (tid >> 6)] = ss;
    __syncthreads();
    float var = (red[4] + red[5] + red[6] + red[7]) * (1.0f / 1024.0f);
    float rstd = 1.0f / sqrtf(var + 1e-6f);
    int d = tid * 4;
    float4 g4 = *(const float4*)&gam[d];
    float4 b4 = *(const float4*)&bet[d];
    float4 o4;
    o4.x = d0 * rstd * g4.x + b4.x;
    o4.y = d1 * rstd * g4.y + b4.y;
    o4.z = d2 * rstd * g4.z + b4.z;
    o4.w = d3 * rstd * g4.w + b4.w;
    *(float4*)&out[(size_t)t * 1024 + d] = o4;
    if (outbf) {
        ushort4 ob;
        ob.x = f2bf(o4.x); ob.y = f2bf(o4.y); ob.z = f2bf(o4.z); ob.w = f2bf(o4.w);
        *(ushort4*)&outbf[(size_t)t * 1024 + d] = ob;
    }
}

// ---------------- bf16 MFMA GEMM: C[4096,N] = A[4096,K]bf16 @ Bt[N,K]bf16^T (+bias)(+resid) ----------------
__global__ __launch_bounds__(256) void gemm_mfma_kernel(const u16* __restrict__ A,
                                                        const u16* __restrict__ Bt,
                                                        const float* __restrict__ bias,
                                                        const float* __restrict__ resid,
                                                        float* __restrict__ C, int N, int K)
{
    __shared__ __align__(16) u16 sA[128 * 80];
    __shared__ __align__(16) u16 sB[128 * 80];
    int n0 = blockIdx.x * 128, m0 = blockIdx.y * 128;
    int tid = threadIdx.x;
    int l = tid & 63, wid = tid >> 6;
    int wm = wid >> 1, wn = wid & 1;
    int l15 = l & 15, hi4 = l >> 4;
    f32x4 acc[4][4];
    #pragma unroll
    for (int i = 0; i < 4; ++i)
        #pragma unroll
        for (int j = 0; j < 4; ++j)
            #pragma unroll
            for (int q = 0; q < 4; ++q) acc[i][j][q] = 0.f;

    int sr = tid >> 1, scb = (tid & 1) * 4;
    for (int k0 = 0; k0 < K; k0 += 64) {
        __syncthreads();
        #pragma unroll
        for (int j = 0; j < 4; ++j) {
            int ch = scb + j;
            uint4 va = *(const uint4*)&A[(size_t)(m0 + sr) * K + k0 + ch * 8];
            *(uint4*)&sA[sr * 80 + ch * 8] = va;
            uint4 vb = *(const uint4*)&Bt[(size_t)(n0 + sr) * K + k0 + ch * 8];
            *(uint4*)&sB[sr * 80 + ch * 8] = vb;
        }
        __syncthreads();
        #pragma unroll
        for (int kc = 0; kc < 2; ++kc) {
            s16x8 af[4], bf[4];
            #pragma unroll
            for (int mf = 0; mf < 4; ++mf)
                af[mf] = *(const s16x8*)&sA[(wm * 64 + mf * 16 + l15) * 80 + kc * 32 + hi4 * 8];
            #pragma unroll
            for (int nf = 0; nf < 4; ++nf)
                bf[nf] = *(const s16x8*)&sB[(wn * 64 + nf * 16 + l15) * 80 + kc * 32 + hi4 * 8];
            #pragma unroll
            for (int mf = 0; mf < 4; ++mf)
                #pragma unroll
                for (int nf = 0; nf < 4; ++nf)
                    acc[mf][nf] = MFMA16(af[mf], bf[nf], acc[mf][nf]);
        }
    }
    #pragma unroll
    for (int mf = 0; mf < 4; ++mf)
        #pragma unroll
        for (int nf = 0; nf < 4; ++nf)
            #pragma unroll
            for (int j = 0; j < 4; ++j) {
                int row = m0 + wm * 64 + mf * 16 + hi4 * 4 + j;
                int col = n0 + wn * 64 + nf * 16 + l15;
                float v = acc[mf][nf][j];
                if (bias) v += bias[col];
                if (resid) v += resid[(size_t)row * N + col];
                C[(size_t)row * N + col] = v;
            }
}

// ---------------- tiny projection ----------------
__global__ __launch_bounds__(64) void vecproj_kernel(const float* __restrict__ h,
                                                     const float* __restrict__ W,
                                                     const float* __restrict__ bias,
                                                     float* __restrict__ out, int nw)
{
    int t = blockIdx.x, lane = threadIdx.x;
    float p0 = 0.f, p1 = 0.f, p2 = 0.f;
    #pragma unroll
    for (int it = 0; it < 4; ++it) {
        int d = it * 256 + lane * 4;
        float4 h4 = *(const float4*)&h[(size_t)t * 1024 + d];
        if (nw == 1) {
            float4 w4 = *(const float4*)&W[d];
            p0 += h4.x * w4.x + h4.y * w4.y + h4.z * w4.z + h4.w * w4.w;
        } else {
            float4 w0 = *(const float4*)&W[d * 3];
            float4 w1 = *(const float4*)&W[d * 3 + 4];
            float4 w2 = *(const float4*)&W[d * 3 + 8];
            p0 += h4.x * w0.x + h4.y * w0.w + h4.z * w1.z + h4.w * w2.y;
            p1 += h4.x * w0.y + h4.y * w1.x + h4.z * w1.w + h4.w * w2.z;
            p2 += h4.x * w0.z + h4.y * w1.y + h4.z * w2.x + h4.w * w2.w;
        }
    }
    #pragma unroll
    for (int o = 1; o < 64; o <<= 1) {
        p0 += __shfl_xor(p0, o);
        p1 += __shfl_xor(p1, o);
        p2 += __shfl_xor(p2, o);
    }
    if (lane == 0) {
        out[(size_t)t * nw + 0] = p0 + bias[0];
        if (nw > 1) out[(size_t)t * nw + 1] = p1 + bias[1];
        if (nw > 2) out[(size_t)t * nw + 2] = p2 + bias[2];
    }
}

// ---------------- hierarchical gate v6: one wave per token, ZERO global atomics ----------------
// Fused over gates via blockIdx.y (gy): hoff=gy*128, tauoff=gy, emb/ceT advance at gy==2.
// Cluster probs written as plain rows to cprob; nfreq deferred to nfreq_partial_kernel.
template<int NCAND, int LGCS>
__global__ __launch_bounds__(256) void gate_wave_kernel(
    const float* __restrict__ hsrc, int hstride,
    const float* __restrict__ tausrc, int taustride,
    const u16* __restrict__ emb16, const float* __restrict__ ceT,
    float* __restrict__ cprob,
    int* __restrict__ gidx, float* __restrict__ gval, int* __restrict__ gcnt)
{
    constexpr int CSM = (1 << LGCS) - 1;
    __shared__ float lds_h[4][128];
    __shared__ float lds_scs[4][NCAND];
    __shared__ int   lds_hist[4][256];
    __shared__ int   lds_topc[4][8];

    int gy = blockIdx.y;
    const u16* emb = emb16 + ((size_t)(gy >> 1)) * 4096 * 128;
    const float* ce = ceT + (gy >> 1) * (128 * 64);
    int hoff = gy * 128, tauoff = gy;
    cprob += (size_t)gy * NTOK * 64;
    gidx  += (size_t)gy * NTOK * CAP;
    gval  += (size_t)gy * NTOK * CAP;
    gcnt  += gy * NTOK;

    int w = threadIdx.x >> 6, lane = threadIdx.x & 63;
    int t = blockIdx.x * 4 + w;
    int l15 = lane & 15, hi4 = lane >> 4;

    // A: stage h (wave-local)
    {
        float2 hv = *(const float2*)&hsrc[(size_t)t * hstride + hoff + lane * 2];
        *(float2*)&lds_h[w][lane * 2] = hv;
    }

    // B: cluster score, lane = cluster (exact f32)
    float score = 0.f;
    #pragma unroll 8
    for (int d = 0; d < 128; ++d)
        score = fmaf(lds_h[w][d], ce[d * 64 + lane], score);

    // C: softmax probs -> plain coalesced row write (no atomics)
    {
        float mx = score;
        #pragma unroll
        for (int o = 1; o < 64; o <<= 1) mx = fmaxf(mx, __shfl_xor(mx, o));
        float e = expf(score - mx);
        float sm = e;
        #pragma unroll
        for (int o = 1; o < 64; o <<= 1) sm += __shfl_xor(sm, o);
        cprob[(size_t)t * 64 + lane] = e / sm;
    }

    // D: top-8 by parallel rank count (ties -> lowest index)
    {
        int rank = 0;
        for (int j = 0; j < 64; ++j) {
            float sj = __shfl(score, j);
            rank += (sj > score || (sj == score && j < lane)) ? 1 : 0;
        }
        if (rank < 8) lds_topc[w][rank] = lane;
    }

    // E: h as bf16 MFMA B-operand (col 0 only)
    s16x8 bfr[4];
    #pragma unroll
    for (int c = 0; c < 4; ++c) {
        #pragma unroll
        for (int j = 0; j < 8; ++j)
            bfr[c][j] = (l15 == 0) ? (short)f2bf(lds_h[w][c * 32 + hi4 * 8 + j]) : (short)0;
    }

    // F: MFMA candidate scoring, 16 neurons per iteration
    #pragma unroll 2
    for (int g2 = 0; g2 < NCAND / 16; ++g2) {
        int i = g2 * 16 + l15;
        int id = (lds_topc[w][i >> LGCS] << LGCS) + (i & CSM);
        const u16* brow = emb + (size_t)id * 128 + hi4 * 8;
        s16x8 a0 = *(const s16x8*)&brow[0];
        s16x8 a1 = *(const s16x8*)&brow[32];
        s16x8 a2 = *(const s16x8*)&brow[64];
        s16x8 a3 = *(const s16x8*)&brow[96];
        f32x4 d = {0.f, 0.f, 0.f, 0.f};
        d = MFMA16(a0, bfr[0], d);
        d = MFMA16(a1, bfr[1], d);
        d = MFMA16(a2, bfr[2], d);
        d = MFMA16(a3, bfr[3], d);
        if (l15 == 0) {
            #pragma unroll
            for (int j = 0; j < 4; ++j)
                lds_scs[w][g2 * 16 + hi4 * 4 + j] = d[j];
        }
    }

    // G: wave-local radix select of the 128-th largest score (exact bits)
    unsigned prefix = 0; int k = 128;
    #pragma unroll
    for (int shift = 24; shift >= 0; shift -= 8) {
        lds_hist[w][lane] = 0;
        lds_hist[w][lane + 64] = 0;
        lds_hist[w][lane + 128] = 0;
        lds_hist[w][lane + 192] = 0;
        unsigned mhi = (shift == 24) ? 0u : (0xFFFFFFFFu << (shift + 8));
        #pragma unroll
        for (int ii = 0; ii < NCAND; ii += 64) {
            unsigned key = mapkey(lds_scs[w][ii + lane]);
            if ((key & mhi) == prefix) atomicAdd(&lds_hist[w][(key >> shift) & 255], 1);
        }
        int s0 = lds_hist[w][4 * lane], s1 = lds_hist[w][4 * lane + 1];
        int s2 = lds_hist[w][4 * lane + 2], s3 = lds_hist[w][4 * lane + 3];
        int sl = s0 + s1 + s2 + s3;
        int suf = sl;
        #pragma unroll
        for (int o = 1; o < 64; o <<= 1) {
            int ov = __shfl_down(suf, o);
            if (lane + o < 64) suf += ov;
        }
        int run = suf - sl;
        int seld = -1, selk = 0;
        if (run < k && k <= run + s3) { seld = 4 * lane + 3; selk = k - run; }
        run += s3;
        if (seld < 0 && run < k && k <= run + s2) { seld = 4 * lane + 2; selk = k - run; }
        run += s2;
        if (seld < 0 && run < k && k <= run + s1) { seld = 4 * lane + 1; selk = k - run; }
        run += s1;
        if (seld < 0 && run < k && k <= run + s0) { seld = 4 * lane + 0; selk = k - run; }
        u64 mk = __ballot(seld >= 0);
        int owner = __ffsll(mk) - 1;
        int sd = __shfl(seld, owner);
        k = __shfl(selk, owner);
        prefix |= ((unsigned)sd) << shift;
    }
    unsigned thrkey = prefix;

    // H: collect kept via ballot compaction; exp only for kept
    float tau = tausrc[(size_t)t * taustride + tauoff];
    int basec = 0;
    float lsum = 0.f, lmaxs = -3.0e38f;
    #pragma unroll
    for (int c0 = 0; c0 < NCAND; c0 += 64) {
        float s = lds_scs[w][c0 + lane];
        lmaxs = fmaxf(lmaxs, s);
        bool pred = (mapkey(s) >= thrkey);
        float eg = 0.f;
        if (pred) {
            float raw = s - tau;
            float g2 = raw > 0.f ? raw : 1e-8f * expf(raw);
            eg = expf(g2) - 1.0f;
            lsum += eg;
        }
        u64 mk = __ballot(pred);
        int pos = basec + __popcll(mk & ((1ull << lane) - 1ull));
        if (pred && pos < CAP) {
            lds_hist[w][pos] = c0 + lane;
            lds_scs[w][pos] = eg;
        }
        basec += __popcll(mk);
    }
    #pragma unroll
    for (int o = 1; o < 64; o <<= 1) {
        lsum += __shfl_xor(lsum, o);
        lmaxs = fmaxf(lmaxs, __shfl_xor(lmaxs, o));
    }
    float rawm = lmaxs - tau;
    float gm = rawm > 0.f ? rawm : 1e-8f * expf(rawm);
    float egm = expf(gm) - 1.0f;
    float scalev = tanhf(egm) / (lsum + 1e-8f);
    int nkept = basec < CAP ? basec : CAP;

    // I: write out (no atomics)
    for (int p = lane; p < nkept; p += 64) {
        int i = lds_hist[w][p];
        float eg = lds_scs[w][p];
        int neuron = (lds_topc[w][i >> LGCS] << LGCS) + (i & CSM);
        gidx[(size_t)t * CAP + p] = neuron;
        gval[(size_t)t * CAP + p] = eg * scalev;
    }
    if (lane == 0) gcnt[t] = nkept;
}

// ---------------- nfreq partials: LDS scatter-accumulate of (gidx,gval), no global atomics ----------------
// grid (64 slices, 4 gates), block 256. partials layout [gate][copy=64][8192].
__global__ __launch_bounds__(256) void nfreq_partial_kernel(
    const int* __restrict__ gidx, const float* __restrict__ gval,
    const int* __restrict__ gcnt, float* __restrict__ partials)
{
    __shared__ float hist[8192];
    int slice = blockIdx.x, gate = blockIdx.y;
    int N = (gate == 3) ? 8192 : 4096;
    int tid = threadIdx.x;
    for (int i = tid; i < N; i += 256) hist[i] = 0.f;
    __syncthreads();
    int w = tid >> 6, lane = tid & 63;
    const int* gi = gidx + (size_t)gate * NTOK * CAP;
    const float* gv = gval + (size_t)gate * NTOK * CAP;
    const int* gc = gcnt + gate * NTOK;
    #pragma unroll 4
    for (int i = 0; i < 16; ++i) {
        int t = slice * 64 + i * 4 + w;
        int cnt = gc[t];
        for (int p = lane; p < cnt; p += 64) {
            int n = gi[(size_t)t * CAP + p];
            float v = gv[(size_t)t * CAP + p];
            atomicAdd(&hist[n], v);
        }
    }
    __syncthreads();
    float* op = partials + ((size_t)gate * 64 + slice) * 8192;
    for (int i = tid; i < N; i += 256) op[i] = hist[i];
}

// ---------------- aux: reduce cprob + nfreq partials -> single scalar (68 blocks, 68 atomics) ----------------
__global__ __launch_bounds__(256) void aux2_kernel(const float* __restrict__ partials,
                                                   const float* __restrict__ cprob,
                                                   float* __restrict__ outp)
{
    __shared__ float red[4];
    __shared__ float cred[4][64];
    int bid = blockIdx.x, tid = threadIdx.x;
    float local = 0.f;
    if (bid < 64) {
        // neurons [bid*320, bid*320+320) of global 20480 (3x4096 + 8192)
        #pragma unroll
        for (int r = 0; r < 320; r += 256) {
            int gn = bid * 320 + r + tid;
            if ((r + tid) < 320) {
                int gate = (gn < 12288) ? (gn >> 12) : 3;
                int ln = (gn < 12288) ? (gn & 4095) : (gn - 12288);
                const float* base = partials + (size_t)gate * 64 * 8192 + ln;
                float s = 0.f;
                #pragma unroll 8
                for (int c = 0; c < 64; ++c) s += base[(size_t)c * 8192];
                float Nf = (gate == 3) ? 8192.f : 4096.f;
                float f = s * (1.0f / 4096.0f);
                float d = f - 1.0f / Nf;
                local += d * d * Nf;
            }
        }
    } else {
        int gate = bid - 64;
        int w = tid >> 6, lane = tid & 63;
        const float* cp = cprob + (size_t)gate * NTOK * 64;
        float s = 0.f;
        for (int t = w; t < NTOK; t += 4) s += cp[(size_t)t * 64 + lane];
        cred[w][lane] = s;
        __syncthreads();
        if (tid < 64) {
            float tot = cred[0][tid] + cred[1][tid] + cred[2][tid] + cred[3][tid];
            float f = tot * (1.0f / 4096.0f);
            float d = f - (1.0f / 64.0f);
            local = d * d * 64.0f;
        }
    }
    #pragma unroll
    for (int o = 1; o < 64; o <<= 1) local += __shfl_xor(local, o);
    if ((tid & 63) == 0) red[tid >> 6] = local;
    __syncthreads();
    if (tid == 0) atomicAdd(outp, red[0] + red[1] + red[2] + red[3]);
}

// ---------------- sparse sense_emit, one block per token, 4-neuron unroll ----------------
__global__ __launch_bounds__(256) void sense_emit_kernel(
    const float* __restrict__ h, const int* __restrict__ gidx,
    const float* __restrict__ gval, const int* __restrict__ gcnt,
    const u16* __restrict__ nbf, u16* __restrict__ outq, float* __restrict__ outadd)
{
    __shared__ float part[4][1024];
    int t = blockIdx.x;
    int w = threadIdx.x >> 6, lane = threadIdx.x & 63;
    float hreg[16], acc[16];
    const float* hrow = h + (size_t)t * 1024 + lane * 16;
    #pragma unroll
    for (int j = 0; j < 16; j += 4) {
        float4 v = *(const float4*)&hrow[j];
        hreg[j] = v.x; hreg[j + 1] = v.y; hreg[j + 2] = v.z; hreg[j + 3] = v.w;
    }
    #pragma unroll
    for (int j = 0; j < 16; ++j) acc[j] = 0.f;
    int cnt = gcnt[t];
    uint4 zz = make_uint4(0u, 0u, 0u, 0u);
    for (int base = w * 4; base < cnt; base += 16) {
        uint4 r0a = zz, r0b = zz, r1a = zz, r1b = zz, r2a = zz, r2b = zz, r3a = zz, r3b = zz;
        float w0 = 0.f, w1 = 0.f, w2 = 0.f, w3 = 0.f;
        if (base + 0 < cnt) {
            int id = gidx[(size_t)t * CAP + base + 0]; w0 = gval[(size_t)t * CAP + base + 0];
            const u16* p = nbf + (size_t)id * 1024 + lane * 16;
            r0a = *(const uint4*)p; r0b = *(const uint4*)(p + 8);
        }
        if (base + 1 < cnt) {
            int id = gidx[(size_t)t * CAP + base + 1]; w1 = gval[(size_t)t * CAP + base + 1];
            const u16* p = nbf + (size_t)id * 1024 + lane * 16;
            r1a = *(const uint4*)p; r1b = *(const uint4*)(p + 8);
        }
        if (base + 2 < cnt) {
            int id = gidx[(size_t)t * CAP + base + 2]; w2 = gval[(size_t)t * CAP + base + 2];
            const u16* p = nbf + (size_t)id * 1024 + lane * 16;
            r2a = *(const uint4*)p; r2b = *(const uint4*)(p + 8);
        }
        if (base + 3 < cnt) {
            int id = gidx[(size_t)t * CAP + base + 3]; w3 = gval[(size_t)t * CAP + base + 3];
            const u16* p = nbf + (size_t)id * 1024 + lane * 16;
            r3a = *(const uint4*)p; r3b = *(const uint4*)(p + 8);
        }
        float n0f[16], n1f[16], n2f[16], n3f[16];
        unpack8(r0a, n0f); unpack8(r0b, n0f + 8);
        unpack8(r1a, n1f); unpack8(r1b, n1f + 8);
        unpack8(r2a, n2f); unpack8(r2b, n2f + 8);
        unpack8(r3a, n3f); unpack8(r3b, n3f + 8);
        float dp0 = 0.f, dp1 = 0.f, dp2 = 0.f, dp3 = 0.f;
        #pragma unroll
        for (int j = 0; j < 16; ++j) {
            dp0 += hreg[j] * n0f[j];
            dp1 += hreg[j] * n1f[j];
            dp2 += hreg[j] * n2f[j];
            dp3 += hreg[j] * n3f[j];
        }
        #pragma unroll
        for (int o = 1; o < 64; o <<= 1) {
            dp0 += __shfl_xor(dp0, o);
            dp1 += __shfl_xor(dp1, o);
            dp2 += __shfl_xor(dp2, o);
            dp3 += __shfl_xor(dp3, o);
        }
        float c0 = dp0 * w0, c1 = dp1 * w1, c2 = dp2 * w2, c3 = dp3 * w3;
        #pragma unroll
        for (int j = 0; j < 16; ++j)
            acc[j] += c0 * n0f[j] + c1 * n1f[j] + c2 * n2f[j] + c3 * n3f[j];
    }
    #pragma unroll
    for (int j = 0; j < 16; j += 4)
        *(float4*)&part[w][lane * 16 + j] = make_float4(acc[j], acc[j + 1], acc[j + 2], acc[j + 3]);
    __syncthreads();
    int d0 = threadIdx.x * 4;
    float4 s0 = *(const float4*)&part[0][d0];
    float4 s1 = *(const float4*)&part[1][d0];
    float4 s2 = *(const float4*)&part[2][d0];
    float4 s3 = *(const float4*)&part[3][d0];
    float4 sum = make_float4(s0.x + s1.x + s2.x + s3.x, s0.y + s1.y + s2.y + s3.y,
                             s0.z + s1.z + s2.z + s3.z, s0.w + s1.w + s2.w + s3.w);
    if (outq) {
        int b = t >> 10, s = t & 1023;
        int head = d0 >> 6, dh = d0 & 63;
        ushort4 o;
        o.x = f2bf(sum.x); o.y = f2bf(sum.y); o.z = f2bf(sum.z); o.w = f2bf(sum.w);
        *(ushort4*)&outq[(((size_t)b * 16 + head) * 1024 + s) * 64 + dh] = o;
    } else {
        float* op = outadd + (size_t)t * 1024 + d0;
        float4 cur = *(const float4*)op;
        cur.x += sum.x; cur.y += sum.y; cur.z += sum.z; cur.w += sum.w;
        *(float4*)op = cur;
    }
}

// ---------------- MFMA flash attention, causal, d=64 ----------------
__global__ __launch_bounds__(256) void attn_kernel(const u16* __restrict__ Qb,
                                                   const u16* __restrict__ Kb,
                                                   const u16* __restrict__ Vb,
                                                   u16* __restrict__ outbf)
{
    __shared__ __align__(16) u32 VT[2048];
    __shared__ float csh[128];
    __shared__ float lsh[128];
    int qt = blockIdx.x;
    int bh = blockIdx.y;
    int b = bh >> 4, hh = bh & 15;
    int tid = threadIdx.x;
    int w = tid >> 6, lane = tid & 63;
    int hi = lane >> 5, l31 = lane & 31;
    int qb = qt * 128;
    int qcol = qb + w * 32 + l31;
    int wqmax = qb + w * 32 + 31;
    int ktmax = 2 * qt + 1;

    const u16* Qbase = Qb + (size_t)bh * 1024 * 64;
    const u16* Kbase = Kb + (size_t)bh * 1024 * 64;
    const u16* Vbase = Vb + (size_t)bh * 1024 * 64;

    s16x8 qf[4];
    #pragma unroll
    for (int c = 0; c < 4; ++c)
        qf[c] = *(const s16x8*)&Qbase[(size_t)qcol * 64 + c * 16 + hi * 8];

    int vkey = 2 * (tid & 31);
    int vd = (tid >> 5) * 8;
    uint4 va  = *(const uint4*)&Vbase[(size_t)vkey * 64 + vd];
    uint4 vb2 = *(const uint4*)&Vbase[(size_t)(vkey + 1) * 64 + vd];

    s16x8 kf[2][4];
    #pragma unroll
    for (int s = 0; s < 2; ++s)
        #pragma unroll
        for (int c = 0; c < 4; ++c)
            kf[s][c] = *(const s16x8*)&Kbase[(size_t)(s * 32 + l31) * 64 + c * 16 + hi * 8];

    float m = -3.0e38f, lden = 0.f;
    f32x16 oacc0, oacc1;
    #pragma unroll
    for (int r = 0; r < 16; ++r) { oacc0[r] = 0.f; oacc1[r] = 0.f; }

    for (int kt = 0; kt <= ktmax; ++kt) {
        __syncthreads();
        {
            U16x8 ua, ub; ua.u = va; ub.u = vb2;
            #pragma unroll
            for (int j = 0; j < 8; ++j) {
                int d = vd + j;
                u32 pk = (u32)ua.s[j] | ((u32)ub.s[j] << 16);
                VT[(u32)((d * 32 + (tid & 31)) ^ ((d & 7) << 2))] = pk;
            }
        }
        __syncthreads();

        bool active = (kt * 64) <= wqmax;
        f32x16 s0, s1;
        if (active) {
            #pragma unroll
            for (int r = 0; r < 16; ++r) { s0[r] = 0.f; s1[r] = 0.f; }
            #pragma unroll
            for (int c = 0; c < 4; ++c) {
                s0 = MFMA32(kf[0][c], qf[c], s0);
                s1 = MFMA32(kf[1][c], qf[c], s1);
            }
        }
        if (kt < ktmax) {
            int nb = (kt + 1) * 64;
            va  = *(const uint4*)&Vbase[(size_t)(nb + vkey) * 64 + vd];
            vb2 = *(const uint4*)&Vbase[(size_t)(nb + vkey + 1) * 64 + vd];
            if (nb <= wqmax) {
                #pragma unroll
                for (int s = 0; s < 2; ++s)
                    #pragma unroll
                    for (int c = 0; c < 4; ++c)
                        kf[s][c] = *(const s16x8*)&Kbase[(size_t)(nb + s * 32 + l31) * 64 + c * 16 + hi * 8];
            }
        }
        if (active) {
            float p0[16], p1[16];
            float pmax = -3.0e38f;
            #pragma unroll
            for (int r = 0; r < 16; ++r) {
                int crow = (r & 3) + 8 * (r >> 2) + 4 * hi;
                int k0 = kt * 64 + crow;
                float v0 = (k0 <= qcol) ? s0[r] * 0.125f : -3.0e38f;
                float v1 = (k0 + 32 <= qcol) ? s1[r] * 0.125f : -3.0e38f;
                p0[r] = v0; p1[r] = v1;
                pmax = fmaxf(pmax, fmaxf(v0, v1));
            }
            pmax = fmaxf(pmax, __shfl_xor(pmax, 32));
            float mn = fmaxf(m, pmax);
            float corr = __expf(m - mn);
            float rs = 0.f;
            #pragma unroll
            for (int r = 0; r < 16; ++r) {
                p0[r] = __expf(p0[r] - mn);
                p1[r] = __expf(p1[r] - mn);
                rs += p0[r] + p1[r];
            }
            rs += __shfl_xor(rs, 32);
            lden = lden * corr + rs;
            m = mn;
            if (hi == 0) csh[w * 32 + l31] = corr;
            float c16[16];
            #pragma unroll
            for (int r = 0; r < 16; ++r)
                c16[r] = csh[w * 32 + ((r & 3) + 8 * (r >> 2) + 4 * hi)];
            #pragma unroll
            for (int r = 0; r < 16; ++r) { oacc0[r] *= c16[r]; oacc1[r] *= c16[r]; }

            #pragma unroll
            for (int sub = 0; sub < 2; ++sub) {
                u32 e[8], x[8];
                #pragma unroll
                for (int j = 0; j < 8; ++j) {
                    float lo = sub ? p1[2 * j] : p0[2 * j];
                    float hi2 = sub ? p1[2 * j + 1] : p0[2 * j + 1];
                    e[j] = pkbf(lo, hi2);
                }
                #pragma unroll
                for (int j = 0; j < 8; ++j) x[j] = (u32)__shfl_xor((int)e[j], 32);
                Dw4 t0, t1;
                t0.d[0] = hi ? x[2] : e[0];
                t0.d[1] = hi ? x[3] : e[1];
                t0.d[2] = hi ? e[2] : x[0];
                t0.d[3] = hi ? e[3] : x[1];
                t1.d[0] = hi ? x[6] : e[4];
                t1.d[1] = hi ? x[7] : e[5];
                t1.d[2] = hi ? e[6] : x[4];
                t1.d[3] = hi ? e[7] : x[5];
                int kb0 = sub * 32 + hi * 8;
                int kb1 = kb0 + 16;
                int d0 = l31, d1 = 32 + l31;
                const char* vtb = (const char*)VT;
                s16x8 vf;
                vf = *(const s16x8*)(vtb + (((d0 * 128 + kb0 * 2)) ^ ((d0 & 7) << 4)));
                oacc0 = MFMA32(t0.v, vf, oacc0);
                vf = *(const s16x8*)(vtb + (((d1 * 128 + kb0 * 2)) ^ ((d1 & 7) << 4)));
                oacc1 = MFMA32(t0.v, vf, oacc1);
                vf = *(const s16x8*)(vtb + (((d0 * 128 + kb1 * 2)) ^ ((d0 & 7) << 4)));
                oacc0 = MFMA32(t1.v, vf, oacc0);
                vf = *(const s16x8*)(vtb + (((d1 * 128 + kb1 * 2)) ^ ((d1 & 7) << 4)));
                oacc1 = MFMA32(t1.v, vf, oacc1);
            }
        }
    }
    if (hi == 0) lsh[w * 32 + l31] = 1.0f / lden;
    float li[16];
    #pragma unroll
    for (int r = 0; r < 16; ++r)
        li[r] = lsh[w * 32 + ((r & 3) + 8 * (r >> 2) + 4 * hi)];
    #pragma unroll
    for (int r = 0; r < 16; ++r) {
        int crow = (r & 3) + 8 * (r >> 2) + 4 * hi;
        size_t token = (size_t)b * 1024 + qb + w * 32 + crow;
        outbf[token * 1024 + hh * 64 + l31]      = f2bf(oacc0[r] * li[r]);
        outbf[token * 1024 + hh * 64 + 32 + l31] = f2bf(oacc1[r] * li[r]);
    }
}

extern "C" void kernel_launch(void* const* d_in, const int* in_sizes, int n_in,
                              void* d_out, int out_size, void* d_ws, size_t ws_size,
                              hipStream_t stream) {
    const float* x            = (const float*)d_in[0];
    const float* neuron_emb   = (const float*)d_in[1];
    const float* proj_attn_k  = (const float*)d_in[2];
    const float* proj_attn_b  = (const float*)d_in[3];
    const float* tau_attn_k   = (const float*)d_in[4];
    const float* tau_attn_b   = (const float*)d_in[5];
    const float* proj_know_k  = (const float*)d_in[6];
    const float* proj_know_b  = (const float*)d_in[7];
    const float* tau_know_k   = (const float*)d_in[8];
    const float* tau_know_b   = (const float*)d_in[9];
    const float* cluster_qk   = (const float*)d_in[10];
    const float* cluster_v    = (const float*)d_in[11];
    const float* cluster_know = (const float*)d_in[12];
    const float* qk_neurons   = (const float*)d_in[13];
    const float* v_neurons    = (const float*)d_in[14];
    const float* know_neurons = (const float*)d_in[15];
    const float* expand_O     = (const float*)d_in[16];
    const float* ln1_s        = (const float*)d_in[17];
    const float* ln1_b        = (const float*)d_in[18];
    const float* ln2_s        = (const float*)d_in[19];
    const float* ln2_b        = (const float*)d_in[20];
    float* out = (float*)d_out;

    char* wsb = (char*)d_ws;
    size_t off = 0;
    auto alloc = [&](size_t bytes) -> void* {
        void* p = wsb + off;
        off = (off + bytes + 255) & ~(size_t)255;
        return p;
    };
    u16*   emb16    = (u16*)alloc((size_t)16384 * 128 * 2);
    float* ceT      = (float*)alloc((size_t)3 * 128 * 64 * 4);
    u16*   nbf      = (u16*)alloc((size_t)16384 * 1024 * 2);
    float* h1       = (float*)alloc((size_t)NTOK * 1024 * 4);
    u16*   h1bf     = (u16*)alloc((size_t)NTOK * 1024 * 2);
    float* h_all    = (float*)alloc((size_t)NTOK * 384 * 4);
    float* tau_all  = (float*)alloc((size_t)NTOK * 3 * 4);
    float* h_know   = (float*)alloc((size_t)NTOK * 128 * 4);
    float* tau_kn   = (float*)alloc((size_t)NTOK * 4);
    int*   gidx     = (int*)alloc((size_t)4 * NTOK * CAP * 4);
    float* gvalp    = (float*)alloc((size_t)4 * NTOK * CAP * 4);
    int*   gcnt     = (int*)alloc((size_t)4 * NTOK * 4);
    u16*   qkv      = (u16*)alloc((size_t)3 * NTOK * 1024 * 2);
    u16*   projA_t  = (u16*)alloc((size_t)384 * 1024 * 2);
    u16*   know_t   = (u16*)alloc((size_t)128 * 1024 * 2);
    u16*   exp_t    = (u16*)alloc((size_t)1024 * 1024 * 2);
    float* cprob    = (float*)alloc((size_t)4 * NTOK * 64 * 4);
    float* partials = (float*)alloc((size_t)4 * 64 * 8192 * 4);

    u16* Qbuf = qkv;
    u16* Kbuf = qkv + (size_t)NTOK * 1024;
    u16* Vbuf = qkv + (size_t)2 * NTOK * 1024;
    u16* attn_bf = h1bf;

    // aux scalar accumulates via atomics -> zero it first
    hipMemsetAsync(out + (size_t)NTOK * 1024, 0, 4, stream);

    norm_rows_kernel<<<16384 / 4, 256, 0, stream>>>(neuron_emb, emb16, nullptr, 16384);
    norm_rows_kernel<<<16, 256, 0, stream>>>(cluster_qk, nullptr, ceT, 64);
    norm_rows_kernel<<<16, 256, 0, stream>>>(cluster_v, nullptr, ceT + 128 * 64, 64);
    norm_rows_kernel<<<16, 256, 0, stream>>>(cluster_know, nullptr, ceT + 2 * 128 * 64, 64);
    cast_bf16_kernel<<<4096, 256, 0, stream>>>(qk_neurons, nbf, 4096 * 1024);
    cast_bf16_kernel<<<4096, 256, 0, stream>>>(v_neurons, nbf + (size_t)4096 * 1024, 4096 * 1024);
    cast_bf16_kernel<<<8192, 256, 0, stream>>>(know_neurons, nbf + (size_t)8192 * 1024, 8192 * 1024);
    transpose_cast_kernel<<<dim3(6, 16), dim3(64, 4), 0, stream>>>(proj_attn_k, projA_t, 384, 1024);
    transpose_cast_kernel<<<dim3(2, 16), dim3(64, 4), 0, stream>>>(proj_know_k, know_t, 128, 1024);
    transpose_cast_kernel<<<dim3(16, 16), dim3(64, 4), 0, stream>>>(expand_O, exp_t, 1024, 1024);

    ln_kernel<<<NTOK, 256, 0, stream>>>(x, ln1_s, ln1_b, h1, h1bf);
    gemm_mfma_kernel<<<dim3(3, 32), 256, 0, stream>>>(h1bf, projA_t, proj_attn_b, nullptr, h_all, 384, 1024);
    vecproj_kernel<<<NTOK, 64, 0, stream>>>(h1, tau_attn_k, tau_attn_b, tau_all, 3);

    // 3 attn gates in ONE dispatch (gy = 0,1,2), zero global atomics
    gate_wave_kernel<512, 6><<<dim3(1024, 3), 256, 0, stream>>>(
        h_all, 384, tau_all, 3, emb16, ceT, cprob, gidx, gvalp, gcnt);

    sense_emit_kernel<<<NTOK, 256, 0, stream>>>(h1, gidx, gvalp, gcnt, nbf, Qbuf, nullptr);
    sense_emit_kernel<<<NTOK, 256, 0, stream>>>(h1, gidx + (size_t)NTOK * CAP, gvalp + (size_t)NTOK * CAP,
                                                gcnt + NTOK, nbf, Kbuf, nullptr);
    sense_emit_kernel<<<NTOK, 256, 0, stream>>>(h1, gidx + (size_t)2 * NTOK * CAP, gvalp + (size_t)2 * NTOK * CAP,
                                                gcnt + 2 * NTOK, nbf + (size_t)4096 * 1024, Vbuf, nullptr);

    attn_kernel<<<dim3(8, 64), 256, 0, stream>>>(Qbuf, Kbuf, Vbuf, attn_bf);
    gemm_mfma_kernel<<<dim3(8, 32), 256, 0, stream>>>(attn_bf, exp_t, nullptr, x, out, 1024, 1024);

    ln_kernel<<<NTOK, 256, 0, stream>>>(out, ln2_s, ln2_b, h1, h1bf);
    gemm_mfma_kernel<<<dim3(1, 32), 256, 0, stream>>>(h1bf, know_t, proj_know_b, nullptr, h_know, 128, 1024);
    vecproj_kernel<<<NTOK, 64, 0, stream>>>(h1, tau_know_k, tau_know_b, tau_kn, 1);
    gate_wave_kernel<1024, 7><<<dim3(1024, 1), 256, 0, stream>>>(
        h_know, 128, tau_kn, 1, emb16 + (size_t)8192 * 128, ceT + 2 * 128 * 64,
        cprob + (size_t)3 * NTOK * 64,
        gidx + (size_t)3 * NTOK * CAP, gvalp + (size_t)3 * NTOK * CAP, gcnt + 3 * NTOK);
    sense_emit_kernel<<<NTOK, 256, 0, stream>>>(h1, gidx + (size_t)3 * NTOK * CAP, gvalp + (size_t)3 * NTOK * CAP,
                                                gcnt + 3 * NTOK, nbf + (size_t)8192 * 1024, nullptr, out);

    // deferred, atomic-free nfreq accumulation + aux reduction
    nfreq_partial_kernel<<<dim3(64, 4), 256, 0, stream>>>(gidx, gvalp, gcnt, partials);
    aux2_kernel<<<68, 256, 0, stream>>>(partials, cprob, out + (size_t)NTOK * 1024);
}

// Round 7
// 1067.081 us; speedup vs baseline: 1.2191x; 1.2191x over previous
//
#include <hip/hip_runtime.h>

typedef unsigned short u16;
typedef unsigned int u32;
typedef unsigned long long u64;
typedef __attribute__((ext_vector_type(8))) short s16x8;
typedef __attribute__((ext_vector_type(4))) float f32x4;
typedef __attribute__((ext_vector_type(16))) float f32x16;

#define NTOK 4096
#define CAP 144

#define MFMA32(a,b,c) __builtin_amdgcn_mfma_f32_32x32x16_bf16(a,b,c,0,0,0)
#define MFMA16(a,b,c) __builtin_amdgcn_mfma_f32_16x16x32_bf16(a,b,c,0,0,0)

union U16x8 { uint4 u; u16 s[8]; };
union Dw4 { u32 d[4]; s16x8 v; };

__device__ __forceinline__ u16 f2bf(float f) {
    u32 u = __float_as_uint(f);
    u32 r = u + 0x7FFFu + ((u >> 16) & 1u);
    return (u16)(r >> 16);
}
__device__ __forceinline__ u32 pkbf(float lo, float hi) {
    u32 r;
    asm("v_cvt_pk_bf16_f32 %0, %1, %2" : "=v"(r) : "v"(lo), "v"(hi));
    return r;
}
__device__ __forceinline__ void unpack8(uint4 u, float* f) {
    f[0] = __uint_as_float(u.x << 16); f[1] = __uint_as_float(u.x & 0xFFFF0000u);
    f[2] = __uint_as_float(u.y << 16); f[3] = __uint_as_float(u.y & 0xFFFF0000u);
    f[4] = __uint_as_float(u.z << 16); f[5] = __uint_as_float(u.z & 0xFFFF0000u);
    f[6] = __uint_as_float(u.w << 16); f[7] = __uint_as_float(u.w & 0xFFFF0000u);
}
__device__ __forceinline__ u32 mapkey(float f) {
    u32 b = __float_as_uint(f);
    return (b & 0x80000000u) ? ~b : (b | 0x80000000u);
}

// ---------------- row L2-normalize (128-wide rows) -> bf16 rows and/or f32 transposed ----------------
__global__ __launch_bounds__(256) void norm_rows_kernel(const float* __restrict__ in,
                                                        u16* __restrict__ out16,
                                                        float* __restrict__ outT, int rows)
{
    int row = blockIdx.x * 4 + (threadIdx.x >> 6);
    int lane = threadIdx.x & 63;
    if (row >= rows) return;
    float2 v = *(const float2*)&in[(size_t)row * 128 + lane * 2];
    float ss = v.x * v.x + v.y * v.y;
    #pragma unroll
    for (int o = 1; o < 64; o <<= 1) ss += __shfl_xor(ss, o);
    float rn = 1.0f / (sqrtf(ss) + 1e-8f);
    float2 ov = make_float2(v.x * rn, v.y * rn);
    if (out16)
        *(u32*)&out16[(size_t)row * 128 + lane * 2] = pkbf(ov.x, ov.y);
    if (outT) {
        outT[(2 * lane) * 64 + row] = ov.x;
        outT[(2 * lane + 1) * 64 + row] = ov.y;
    }
}

// ---------------- f32 -> bf16 cast ----------------
__global__ __launch_bounds__(256) void cast_bf16_kernel(const float* __restrict__ in,
                                                        u16* __restrict__ out, int n)
{
    int i = (blockIdx.x * 256 + threadIdx.x) * 4;
    if (i >= n) return;
    float4 v = *(const float4*)&in[i];
    ushort4 o;
    o.x = f2bf(v.x); o.y = f2bf(v.y); o.z = f2bf(v.z); o.w = f2bf(v.w);
    *(ushort4*)&out[i] = o;
}

// ---------------- transpose + cast: in f32 [Kk][Nn] -> out bf16 [Nn][Kk] ----------------
__global__ void transpose_cast_kernel(const float* __restrict__ in, u16* __restrict__ out,
                                      int Nn, int Kk)
{
    __shared__ float sT[64][65];
    int n0 = blockIdx.x * 64, k0 = blockIdx.y * 64;
    int tx = threadIdx.x, ty = threadIdx.y;
    #pragma unroll
    for (int r = 0; r < 64; r += 4)
        sT[ty + r][tx] = in[(size_t)(k0 + ty + r) * Nn + n0 + tx];
    __syncthreads();
    #pragma unroll
    for (int r = 0; r < 64; r += 4)
        out[(size_t)(n0 + ty + r) * Kk + k0 + tx] = f2bf(sT[tx][ty + r]);
}

// ---------------- LayerNorm over 1024 dims (+fused bf16 copy), one block per token ----------------
__global__ __launch_bounds__(256) void ln_kernel(const float* __restrict__ x,
                                                 const float* __restrict__ gam,
                                                 const float* __restrict__ bet,
                                                 float* __restrict__ out,
                                                 u16* __restrict__ outbf)
{
    __shared__ float red[8];
    int t = blockIdx.x, tid = threadIdx.x;
    const float* row = x + (size_t)t * 1024;
    float4 v = *(const float4*)&row[tid * 4];
    float s = v.x + v.y + v.z + v.w;
    #pragma unroll
    for (int o = 1; o < 64; o <<= 1) s += __shfl_xor(s, o);
    if ((tid & 63) == 0) red[tid >> 6] = s;
    __syncthreads();
    float mean = (red[0] + red[1] + red[2] + red[3]) * (1.0f / 1024.0f);
    float d0 = v.x - mean, d1 = v.y - mean, d2 = v.z - mean, d3 = v.w - mean;
    float ss = d0 * d0 + d1 * d1 + d2 * d2 + d3 * d3;
    #pragma unroll
    for (int o = 1; o < 64; o <<= 1) ss += __shfl_xor(ss, o);
    if ((tid & 63) == 0) red[4 + (tid >> 6)] = ss;
    __syncthreads();
    float var = (red[4] + red[5] + red[6] + red[7]) * (1.0f / 1024.0f);
    float rstd = 1.0f / sqrtf(var + 1e-6f);
    int d = tid * 4;
    float4 g4 = *(const float4*)&gam[d];
    float4 b4 = *(const float4*)&bet[d];
    float4 o4;
    o4.x = d0 * rstd * g4.x + b4.x;
    o4.y = d1 * rstd * g4.y + b4.y;
    o4.z = d2 * rstd * g4.z + b4.z;
    o4.w = d3 * rstd * g4.w + b4.w;
    *(float4*)&out[(size_t)t * 1024 + d] = o4;
    if (outbf) {
        ushort4 ob;
        ob.x = f2bf(o4.x); ob.y = f2bf(o4.y); ob.z = f2bf(o4.z); ob.w = f2bf(o4.w);
        *(ushort4*)&outbf[(size_t)t * 1024 + d] = ob;
    }
}

// ---------------- bf16 MFMA GEMM: C[4096,N] = A[4096,K]bf16 @ Bt[N,K]bf16^T (+bias)(+resid) ----------------
__global__ __launch_bounds__(256) void gemm_mfma_kernel(const u16* __restrict__ A,
                                                        const u16* __restrict__ Bt,
                                                        const float* __restrict__ bias,
                                                        const float* __restrict__ resid,
                                                        float* __restrict__ C, int N, int K)
{
    __shared__ __align__(16) u16 sA[128 * 80];
    __shared__ __align__(16) u16 sB[128 * 80];
    int n0 = blockIdx.x * 128, m0 = blockIdx.y * 128;
    int tid = threadIdx.x;
    int l = tid & 63, wid = tid >> 6;
    int wm = wid >> 1, wn = wid & 1;
    int l15 = l & 15, hi4 = l >> 4;
    f32x4 acc[4][4];
    #pragma unroll
    for (int i = 0; i < 4; ++i)
        #pragma unroll
        for (int j = 0; j < 4; ++j)
            #pragma unroll
            for (int q = 0; q < 4; ++q) acc[i][j][q] = 0.f;

    int sr = tid >> 1, scb = (tid & 1) * 4;
    for (int k0 = 0; k0 < K; k0 += 64) {
        __syncthreads();
        #pragma unroll
        for (int j = 0; j < 4; ++j) {
            int ch = scb + j;
            uint4 va = *(const uint4*)&A[(size_t)(m0 + sr) * K + k0 + ch * 8];
            *(uint4*)&sA[sr * 80 + ch * 8] = va;
            uint4 vb = *(const uint4*)&Bt[(size_t)(n0 + sr) * K + k0 + ch * 8];
            *(uint4*)&sB[sr * 80 + ch * 8] = vb;
        }
        __syncthreads();
        #pragma unroll
        for (int kc = 0; kc < 2; ++kc) {
            s16x8 af[4], bf[4];
            #pragma unroll
            for (int mf = 0; mf < 4; ++mf)
                af[mf] = *(const s16x8*)&sA[(wm * 64 + mf * 16 + l15) * 80 + kc * 32 + hi4 * 8];
            #pragma unroll
            for (int nf = 0; nf < 4; ++nf)
                bf[nf] = *(const s16x8*)&sB[(wn * 64 + nf * 16 + l15) * 80 + kc * 32 + hi4 * 8];
            #pragma unroll
            for (int mf = 0; mf < 4; ++mf)
                #pragma unroll
                for (int nf = 0; nf < 4; ++nf)
                    acc[mf][nf] = MFMA16(af[mf], bf[nf], acc[mf][nf]);
        }
    }
    #pragma unroll
    for (int mf = 0; mf < 4; ++mf)
        #pragma unroll
        for (int nf = 0; nf < 4; ++nf)
            #pragma unroll
            for (int j = 0; j < 4; ++j) {
                int row = m0 + wm * 64 + mf * 16 + hi4 * 4 + j;
                int col = n0 + wn * 64 + nf * 16 + l15;
                float v = acc[mf][nf][j];
                if (bias) v += bias[col];
                if (resid) v += resid[(size_t)row * N + col];
                C[(size_t)row * N + col] = v;
            }
}

// ---------------- tiny projection ----------------
__global__ __launch_bounds__(64) void vecproj_kernel(const float* __restrict__ h,
                                                     const float* __restrict__ W,
                                                     const float* __restrict__ bias,
                                                     float* __restrict__ out, int nw)
{
    int t = blockIdx.x, lane = threadIdx.x;
    float p0 = 0.f, p1 = 0.f, p2 = 0.f;
    #pragma unroll
    for (int it = 0; it < 4; ++it) {
        int d = it * 256 + lane * 4;
        float4 h4 = *(const float4*)&h[(size_t)t * 1024 + d];
        if (nw == 1) {
            float4 w4 = *(const float4*)&W[d];
            p0 += h4.x * w4.x + h4.y * w4.y + h4.z * w4.z + h4.w * w4.w;
        } else {
            float4 w0 = *(const float4*)&W[d * 3];
            float4 w1 = *(const float4*)&W[d * 3 + 4];
            float4 w2 = *(const float4*)&W[d * 3 + 8];
            p0 += h4.x * w0.x + h4.y * w0.w + h4.z * w1.z + h4.w * w2.y;
            p1 += h4.x * w0.y + h4.y * w1.x + h4.z * w1.w + h4.w * w2.z;
            p2 += h4.x * w0.z + h4.y * w1.y + h4.z * w2.x + h4.w * w2.w;
        }
    }
    #pragma unroll
    for (int o = 1; o < 64; o <<= 1) {
        p0 += __shfl_xor(p0, o);
        p1 += __shfl_xor(p1, o);
        p2 += __shfl_xor(p2, o);
    }
    if (lane == 0) {
        out[(size_t)t * nw + 0] = p0 + bias[0];
        if (nw > 1) out[(size_t)t * nw + 1] = p1 + bias[1];
        if (nw > 2) out[(size_t)t * nw + 2] = p2 + bias[2];
    }
}

// ---------------- hierarchical gate v6: one wave per token, ZERO global atomics ----------------
template<int NCAND, int LGCS>
__global__ __launch_bounds__(256) void gate_wave_kernel(
    const float* __restrict__ hsrc, int hstride,
    const float* __restrict__ tausrc, int taustride,
    const u16* __restrict__ emb16, const float* __restrict__ ceT,
    float* __restrict__ cprob,
    int* __restrict__ gidx, float* __restrict__ gval, int* __restrict__ gcnt)
{
    constexpr int CSM = (1 << LGCS) - 1;
    __shared__ float lds_h[4][128];
    __shared__ float lds_scs[4][NCAND];
    __shared__ int   lds_hist[4][256];
    __shared__ int   lds_topc[4][8];

    int gy = blockIdx.y;
    const u16* emb = emb16 + ((size_t)(gy >> 1)) * 4096 * 128;
    const float* ce = ceT + (gy >> 1) * (128 * 64);
    int hoff = gy * 128, tauoff = gy;
    cprob += (size_t)gy * NTOK * 64;
    gidx  += (size_t)gy * NTOK * CAP;
    gval  += (size_t)gy * NTOK * CAP;
    gcnt  += gy * NTOK;

    int w = threadIdx.x >> 6, lane = threadIdx.x & 63;
    int t = blockIdx.x * 4 + w;
    int l15 = lane & 15, hi4 = lane >> 4;

    {
        float2 hv = *(const float2*)&hsrc[(size_t)t * hstride + hoff + lane * 2];
        *(float2*)&lds_h[w][lane * 2] = hv;
    }

    float score = 0.f;
    #pragma unroll 8
    for (int d = 0; d < 128; ++d)
        score = fmaf(lds_h[w][d], ce[d * 64 + lane], score);

    {
        float mx = score;
        #pragma unroll
        for (int o = 1; o < 64; o <<= 1) mx = fmaxf(mx, __shfl_xor(mx, o));
        float e = expf(score - mx);
        float sm = e;
        #pragma unroll
        for (int o = 1; o < 64; o <<= 1) sm += __shfl_xor(sm, o);
        cprob[(size_t)t * 64 + lane] = e / sm;
    }

    {
        int rank = 0;
        for (int j = 0; j < 64; ++j) {
            float sj = __shfl(score, j);
            rank += (sj > score || (sj == score && j < lane)) ? 1 : 0;
        }
        if (rank < 8) lds_topc[w][rank] = lane;
    }

    s16x8 bfr[4];
    #pragma unroll
    for (int c = 0; c < 4; ++c) {
        #pragma unroll
        for (int j = 0; j < 8; ++j)
            bfr[c][j] = (l15 == 0) ? (short)f2bf(lds_h[w][c * 32 + hi4 * 8 + j]) : (short)0;
    }

    #pragma unroll 2
    for (int g2 = 0; g2 < NCAND / 16; ++g2) {
        int i = g2 * 16 + l15;
        int id = (lds_topc[w][i >> LGCS] << LGCS) + (i & CSM);
        const u16* brow = emb + (size_t)id * 128 + hi4 * 8;
        s16x8 a0 = *(const s16x8*)&brow[0];
        s16x8 a1 = *(const s16x8*)&brow[32];
        s16x8 a2 = *(const s16x8*)&brow[64];
        s16x8 a3 = *(const s16x8*)&brow[96];
        f32x4 d = {0.f, 0.f, 0.f, 0.f};
        d = MFMA16(a0, bfr[0], d);
        d = MFMA16(a1, bfr[1], d);
        d = MFMA16(a2, bfr[2], d);
        d = MFMA16(a3, bfr[3], d);
        if (l15 == 0) {
            #pragma unroll
            for (int j = 0; j < 4; ++j)
                lds_scs[w][g2 * 16 + hi4 * 4 + j] = d[j];
        }
    }

    unsigned prefix = 0; int k = 128;
    #pragma unroll
    for (int shift = 24; shift >= 0; shift -= 8) {
        lds_hist[w][lane] = 0;
        lds_hist[w][lane + 64] = 0;
        lds_hist[w][lane + 128] = 0;
        lds_hist[w][lane + 192] = 0;
        unsigned mhi = (shift == 24) ? 0u : (0xFFFFFFFFu << (shift + 8));
        #pragma unroll
        for (int ii = 0; ii < NCAND; ii += 64) {
            unsigned key = mapkey(lds_scs[w][ii + lane]);
            if ((key & mhi) == prefix) atomicAdd(&lds_hist[w][(key >> shift) & 255], 1);
        }
        int s0 = lds_hist[w][4 * lane], s1 = lds_hist[w][4 * lane + 1];
        int s2 = lds_hist[w][4 * lane + 2], s3 = lds_hist[w][4 * lane + 3];
        int sl = s0 + s1 + s2 + s3;
        int suf = sl;
        #pragma unroll
        for (int o = 1; o < 64; o <<= 1) {
            int ov = __shfl_down(suf, o);
            if (lane + o < 64) suf += ov;
        }
        int run = suf - sl;
        int seld = -1, selk = 0;
        if (run < k && k <= run + s3) { seld = 4 * lane + 3; selk = k - run; }
        run += s3;
        if (seld < 0 && run < k && k <= run + s2) { seld = 4 * lane + 2; selk = k - run; }
        run += s2;
        if (seld < 0 && run < k && k <= run + s1) { seld = 4 * lane + 1; selk = k - run; }
        run += s1;
        if (seld < 0 && run < k && k <= run + s0) { seld = 4 * lane + 0; selk = k - run; }
        u64 mk = __ballot(seld >= 0);
        int owner = __ffsll(mk) - 1;
        int sd = __shfl(seld, owner);
        k = __shfl(selk, owner);
        prefix |= ((unsigned)sd) << shift;
    }
    unsigned thrkey = prefix;

    float tau = tausrc[(size_t)t * taustride + tauoff];
    int basec = 0;
    float lsum = 0.f, lmaxs = -3.0e38f;
    #pragma unroll
    for (int c0 = 0; c0 < NCAND; c0 += 64) {
        float s = lds_scs[w][c0 + lane];
        lmaxs = fmaxf(lmaxs, s);
        bool pred = (mapkey(s) >= thrkey);
        float eg = 0.f;
        if (pred) {
            float raw = s - tau;
            float g2 = raw > 0.f ? raw : 1e-8f * expf(raw);
            eg = expf(g2) - 1.0f;
            lsum += eg;
        }
        u64 mk = __ballot(pred);
        int pos = basec + __popcll(mk & ((1ull << lane) - 1ull));
        if (pred && pos < CAP) {
            lds_hist[w][pos] = c0 + lane;
            lds_scs[w][pos] = eg;
        }
        basec += __popcll(mk);
    }
    #pragma unroll
    for (int o = 1; o < 64; o <<= 1) {
        lsum += __shfl_xor(lsum, o);
        lmaxs = fmaxf(lmaxs, __shfl_xor(lmaxs, o));
    }
    float rawm = lmaxs - tau;
    float gm = rawm > 0.f ? rawm : 1e-8f * expf(rawm);
    float egm = expf(gm) - 1.0f;
    float scalev = tanhf(egm) / (lsum + 1e-8f);
    int nkept = basec < CAP ? basec : CAP;

    for (int p = lane; p < nkept; p += 64) {
        int i = lds_hist[w][p];
        float eg = lds_scs[w][p];
        int neuron = (lds_topc[w][i >> LGCS] << LGCS) + (i & CSM);
        gidx[(size_t)t * CAP + p] = neuron;
        gval[(size_t)t * CAP + p] = eg * scalev;
    }
    if (lane == 0) gcnt[t] = nkept;
}

// ---------------- nfreq partials + cprob partial sums (LDS, no global atomics) ----------------
// grid (64 slices, 4 gates), block 256. partials [gate][64][8192]; cpart2 [gate][64][64].
__global__ __launch_bounds__(256) void nfreq_partial_kernel(
    const int* __restrict__ gidx, const float* __restrict__ gval,
    const int* __restrict__ gcnt, const float* __restrict__ cprob,
    float* __restrict__ partials, float* __restrict__ cpart2)
{
    __shared__ float hist[8192];
    __shared__ float csum[4][64];
    int slice = blockIdx.x, gate = blockIdx.y;
    int N = (gate == 3) ? 8192 : 4096;
    int tid = threadIdx.x;
    int w = tid >> 6, lane = tid & 63;
    for (int i = tid; i < N; i += 256) hist[i] = 0.f;

    // cprob partial sums for this slice's 64 tokens (coalesced)
    {
        const float* cp = cprob + (size_t)gate * NTOK * 64;
        float cs = 0.f;
        #pragma unroll
        for (int i = 0; i < 16; ++i) {
            int t = slice * 64 + i * 4 + w;
            cs += cp[(size_t)t * 64 + lane];
        }
        csum[w][lane] = cs;
    }
    __syncthreads();

    const int* gi = gidx + (size_t)gate * NTOK * CAP;
    const float* gv = gval + (size_t)gate * NTOK * CAP;
    const int* gc = gcnt + gate * NTOK;
    #pragma unroll 4
    for (int i = 0; i < 16; ++i) {
        int t = slice * 64 + i * 4 + w;
        int cnt = gc[t];
        for (int p = lane; p < cnt; p += 64) {
            int n = gi[(size_t)t * CAP + p];
            float v = gv[(size_t)t * CAP + p];
            atomicAdd(&hist[n], v);
        }
    }
    __syncthreads();
    float* op = partials + ((size_t)gate * 64 + slice) * 8192;
    for (int i = tid; i < N; i += 256) op[i] = hist[i];
    if (tid < 64)
        cpart2[((size_t)gate * 64 + slice) * 64 + tid] =
            csum[0][tid] + csum[1][tid] + csum[2][tid] + csum[3][tid];
}

// ---------------- aux v3: parallel reduce (84 blocks) ----------------
// blocks 0..79: one neuron per thread (80*256 = 20480). blocks 80..83: cpart2 per gate.
__global__ __launch_bounds__(256) void aux2_kernel(const float* __restrict__ partials,
                                                   const float* __restrict__ cpart2,
                                                   float* __restrict__ outp)
{
    __shared__ float red[4];
    __shared__ float cred[4][64];
    int bid = blockIdx.x, tid = threadIdx.x;
    float local = 0.f;
    if (bid < 80) {
        int gn = bid * 256 + tid;
        int gate = (gn < 12288) ? (gn >> 12) : 3;
        int ln = (gn < 12288) ? (gn & 4095) : (gn - 12288);
        const float* base = partials + (size_t)gate * 64 * 8192 + ln;
        float s = 0.f;
        #pragma unroll 8
        for (int c = 0; c < 64; ++c) s += base[(size_t)c * 8192];
        float Nf = (gate == 3) ? 8192.f : 4096.f;
        float f = s * (1.0f / 4096.0f);
        float d = f - 1.0f / Nf;
        local = d * d * Nf;
    } else {
        int gate = bid - 80;
        int w = tid >> 6, lane = tid & 63;
        const float* base = cpart2 + (size_t)gate * 64 * 64;
        float s = 0.f;
        #pragma unroll
        for (int i = 0; i < 16; ++i) s += base[(size_t)(i * 4 + w) * 64 + lane];
        cred[w][lane] = s;
        __syncthreads();
        if (tid < 64) {
            float tot = cred[0][tid] + cred[1][tid] + cred[2][tid] + cred[3][tid];
            float f = tot * (1.0f / 4096.0f);
            float d = f - (1.0f / 64.0f);
            local = d * d * 64.0f;
        }
    }
    #pragma unroll
    for (int o = 1; o < 64; o <<= 1) local += __shfl_xor(local, o);
    if ((tid & 63) == 0) red[tid >> 6] = local;
    __syncthreads();
    if (tid == 0) atomicAdd(outp, red[0] + red[1] + red[2] + red[3]);
}

// ---------------- sparse sense_emit, one block per token, 4-neuron unroll ----------------
__global__ __launch_bounds__(256) void sense_emit_kernel(
    const float* __restrict__ h, const int* __restrict__ gidx,
    const float* __restrict__ gval, const int* __restrict__ gcnt,
    const u16* __restrict__ nbf, u16* __restrict__ outq, float* __restrict__ outadd)
{
    __shared__ float part[4][1024];
    int t = blockIdx.x;
    int w = threadIdx.x >> 6, lane = threadIdx.x & 63;
    float hreg[16], acc[16];
    const float* hrow = h + (size_t)t * 1024 + lane * 16;
    #pragma unroll
    for (int j = 0; j < 16; j += 4) {
        float4 v = *(const float4*)&hrow[j];
        hreg[j] = v.x; hreg[j + 1] = v.y; hreg[j + 2] = v.z; hreg[j + 3] = v.w;
    }
    #pragma unroll
    for (int j = 0; j < 16; ++j) acc[j] = 0.f;
    int cnt = gcnt[t];
    uint4 zz = make_uint4(0u, 0u, 0u, 0u);
    for (int base = w * 4; base < cnt; base += 16) {
        uint4 r0a = zz, r0b = zz, r1a = zz, r1b = zz, r2a = zz, r2b = zz, r3a = zz, r3b = zz;
        float w0 = 0.f, w1 = 0.f, w2 = 0.f, w3 = 0.f;
        if (base + 0 < cnt) {
            int id = gidx[(size_t)t * CAP + base + 0]; w0 = gval[(size_t)t * CAP + base + 0];
            const u16* p = nbf + (size_t)id * 1024 + lane * 16;
            r0a = *(const uint4*)p; r0b = *(const uint4*)(p + 8);
        }
        if (base + 1 < cnt) {
            int id = gidx[(size_t)t * CAP + base + 1]; w1 = gval[(size_t)t * CAP + base + 1];
            const u16* p = nbf + (size_t)id * 1024 + lane * 16;
            r1a = *(const uint4*)p; r1b = *(const uint4*)(p + 8);
        }
        if (base + 2 < cnt) {
            int id = gidx[(size_t)t * CAP + base + 2]; w2 = gval[(size_t)t * CAP + base + 2];
            const u16* p = nbf + (size_t)id * 1024 + lane * 16;
            r2a = *(const uint4*)p; r2b = *(const uint4*)(p + 8);
        }
        if (base + 3 < cnt) {
            int id = gidx[(size_t)t * CAP + base + 3]; w3 = gval[(size_t)t * CAP + base + 3];
            const u16* p = nbf + (size_t)id * 1024 + lane * 16;
            r3a = *(const uint4*)p; r3b = *(const uint4*)(p + 8);
        }
        float n0f[16], n1f[16], n2f[16], n3f[16];
        unpack8(r0a, n0f); unpack8(r0b, n0f + 8);
        unpack8(r1a, n1f); unpack8(r1b, n1f + 8);
        unpack8(r2a, n2f); unpack8(r2b, n2f + 8);
        unpack8(r3a, n3f); unpack8(r3b, n3f + 8);
        float dp0 = 0.f, dp1 = 0.f, dp2 = 0.f, dp3 = 0.f;
        #pragma unroll
        for (int j = 0; j < 16; ++j) {
            dp0 += hreg[j] * n0f[j];
            dp1 += hreg[j] * n1f[j];
            dp2 += hreg[j] * n2f[j];
            dp3 += hreg[j] * n3f[j];
        }
        #pragma unroll
        for (int o = 1; o < 64; o <<= 1) {
            dp0 += __shfl_xor(dp0, o);
            dp1 += __shfl_xor(dp1, o);
            dp2 += __shfl_xor(dp2, o);
            dp3 += __shfl_xor(dp3, o);
        }
        float c0 = dp0 * w0, c1 = dp1 * w1, c2 = dp2 * w2, c3 = dp3 * w3;
        #pragma unroll
        for (int j = 0; j < 16; ++j)
            acc[j] += c0 * n0f[j] + c1 * n1f[j] + c2 * n2f[j] + c3 * n3f[j];
    }
    #pragma unroll
    for (int j = 0; j < 16; j += 4)
        *(float4*)&part[w][lane * 16 + j] = make_float4(acc[j], acc[j + 1], acc[j + 2], acc[j + 3]);
    __syncthreads();
    int d0 = threadIdx.x * 4;
    float4 s0 = *(const float4*)&part[0][d0];
    float4 s1 = *(const float4*)&part[1][d0];
    float4 s2 = *(const float4*)&part[2][d0];
    float4 s3 = *(const float4*)&part[3][d0];
    float4 sum = make_float4(s0.x + s1.x + s2.x + s3.x, s0.y + s1.y + s2.y + s3.y,
                             s0.z + s1.z + s2.z + s3.z, s0.w + s1.w + s2.w + s3.w);
    if (outq) {
        int b = t >> 10, s = t & 1023;
        int head = d0 >> 6, dh = d0 & 63;
        ushort4 o;
        o.x = f2bf(sum.x); o.y = f2bf(sum.y); o.z = f2bf(sum.z); o.w = f2bf(sum.w);
        *(ushort4*)&outq[(((size_t)b * 16 + head) * 1024 + s) * 64 + dh] = o;
    } else {
        float* op = outadd + (size_t)t * 1024 + d0;
        float4 cur = *(const float4*)op;
        cur.x += sum.x; cur.y += sum.y; cur.z += sum.z; cur.w += sum.w;
        *(float4*)op = cur;
    }
}

// ---------------- MFMA flash attention, causal, d=64 ----------------
__global__ __launch_bounds__(256) void attn_kernel(const u16* __restrict__ Qb,
                                                   const u16* __restrict__ Kb,
                                                   const u16* __restrict__ Vb,
                                                   u16* __restrict__ outbf)
{
    __shared__ __align__(16) u32 VT[2048];
    __shared__ float csh[128];
    __shared__ float lsh[128];
    int qt = blockIdx.x;
    int bh = blockIdx.y;
    int b = bh >> 4, hh = bh & 15;
    int tid = threadIdx.x;
    int w = tid >> 6, lane = tid & 63;
    int hi = lane >> 5, l31 = lane & 31;
    int qb = qt * 128;
    int qcol = qb + w * 32 + l31;
    int wqmax = qb + w * 32 + 31;
    int ktmax = 2 * qt + 1;

    const u16* Qbase = Qb + (size_t)bh * 1024 * 64;
    const u16* Kbase = Kb + (size_t)bh * 1024 * 64;
    const u16* Vbase = Vb + (size_t)bh * 1024 * 64;

    s16x8 qf[4];
    #pragma unroll
    for (int c = 0; c < 4; ++c)
        qf[c] = *(const s16x8*)&Qbase[(size_t)qcol * 64 + c * 16 + hi * 8];

    int vkey = 2 * (tid & 31);
    int vd = (tid >> 5) * 8;
    uint4 va  = *(const uint4*)&Vbase[(size_t)vkey * 64 + vd];
    uint4 vb2 = *(const uint4*)&Vbase[(size_t)(vkey + 1) * 64 + vd];

    s16x8 kf[2][4];
    #pragma unroll
    for (int s = 0; s < 2; ++s)
        #pragma unroll
        for (int c = 0; c < 4; ++c)
            kf[s][c] = *(const s16x8*)&Kbase[(size_t)(s * 32 + l31) * 64 + c * 16 + hi * 8];

    float m = -3.0e38f, lden = 0.f;
    f32x16 oacc0, oacc1;
    #pragma unroll
    for (int r = 0; r < 16; ++r) { oacc0[r] = 0.f; oacc1[r] = 0.f; }

    for (int kt = 0; kt <= ktmax; ++kt) {
        __syncthreads();
        {
            U16x8 ua, ub; ua.u = va; ub.u = vb2;
            #pragma unroll
            for (int j = 0; j < 8; ++j) {
                int d = vd + j;
                u32 pk = (u32)ua.s[j] | ((u32)ub.s[j] << 16);
                VT[(u32)((d * 32 + (tid & 31)) ^ ((d & 7) << 2))] = pk;
            }
        }
        __syncthreads();

        bool active = (kt * 64) <= wqmax;
        f32x16 s0, s1;
        if (active) {
            #pragma unroll
            for (int r = 0; r < 16; ++r) { s0[r] = 0.f; s1[r] = 0.f; }
            #pragma unroll
            for (int c = 0; c < 4; ++c) {
                s0 = MFMA32(kf[0][c], qf[c], s0);
                s1 = MFMA32(kf[1][c], qf[c], s1);
            }
        }
        if (kt < ktmax) {
            int nb = (kt + 1) * 64;
            va  = *(const uint4*)&Vbase[(size_t)(nb + vkey) * 64 + vd];
            vb2 = *(const uint4*)&Vbase[(size_t)(nb + vkey + 1) * 64 + vd];
            if (nb <= wqmax) {
                #pragma unroll
                for (int s = 0; s < 2; ++s)
                    #pragma unroll
                    for (int c = 0; c < 4; ++c)
                        kf[s][c] = *(const s16x8*)&Kbase[(size_t)(nb + s * 32 + l31) * 64 + c * 16 + hi * 8];
            }
        }
        if (active) {
            float p0[16], p1[16];
            float pmax = -3.0e38f;
            #pragma unroll
            for (int r = 0; r < 16; ++r) {
                int crow = (r & 3) + 8 * (r >> 2) + 4 * hi;
                int k0 = kt * 64 + crow;
                float v0 = (k0 <= qcol) ? s0[r] * 0.125f : -3.0e38f;
                float v1 = (k0 + 32 <= qcol) ? s1[r] * 0.125f : -3.0e38f;
                p0[r] = v0; p1[r] = v1;
                pmax = fmaxf(pmax, fmaxf(v0, v1));
            }
            pmax = fmaxf(pmax, __shfl_xor(pmax, 32));
            float mn = fmaxf(m, pmax);
            float corr = __expf(m - mn);
            float rs = 0.f;
            #pragma unroll
            for (int r = 0; r < 16; ++r) {
                p0[r] = __expf(p0[r] - mn);
                p1[r] = __expf(p1[r] - mn);
                rs += p0[r] + p1[r];
            }
            rs += __shfl_xor(rs, 32);
            lden = lden * corr + rs;
            m = mn;
            if (hi == 0) csh[w * 32 + l31] = corr;
            float c16[16];
            #pragma unroll
            for (int r = 0; r < 16; ++r)
                c16[r] = csh[w * 32 + ((r & 3) + 8 * (r >> 2) + 4 * hi)];
            #pragma unroll
            for (int r = 0; r < 16; ++r) { oacc0[r] *= c16[r]; oacc1[r] *= c16[r]; }

            #pragma unroll
            for (int sub = 0; sub < 2; ++sub) {
                u32 e[8], x[8];
                #pragma unroll
                for (int j = 0; j < 8; ++j) {
                    float lo = sub ? p1[2 * j] : p0[2 * j];
                    float hi2 = sub ? p1[2 * j + 1] : p0[2 * j + 1];
                    e[j] = pkbf(lo, hi2);
                }
                #pragma unroll
                for (int j = 0; j < 8; ++j) x[j] = (u32)__shfl_xor((int)e[j], 32);
                Dw4 t0, t1;
                t0.d[0] = hi ? x[2] : e[0];
                t0.d[1] = hi ? x[3] : e[1];
                t0.d[2] = hi ? e[2] : x[0];
                t0.d[3] = hi ? e[3] : x[1];
                t1.d[0] = hi ? x[6] : e[4];
                t1.d[1] = hi ? x[7] : e[5];
                t1.d[2] = hi ? e[6] : x[4];
                t1.d[3] = hi ? e[7] : x[5];
                int kb0 = sub * 32 + hi * 8;
                int kb1 = kb0 + 16;
                int d0 = l31, d1 = 32 + l31;
                const char* vtb = (const char*)VT;
                s16x8 vf;
                vf = *(const s16x8*)(vtb + (((d0 * 128 + kb0 * 2)) ^ ((d0 & 7) << 4)));
                oacc0 = MFMA32(t0.v, vf, oacc0);
                vf = *(const s16x8*)(vtb + (((d1 * 128 + kb0 * 2)) ^ ((d1 & 7) << 4)));
                oacc1 = MFMA32(t0.v, vf, oacc1);
                vf = *(const s16x8*)(vtb + (((d0 * 128 + kb1 * 2)) ^ ((d0 & 7) << 4)));
                oacc0 = MFMA32(t1.v, vf, oacc0);
                vf = *(const s16x8*)(vtb + (((d1 * 128 + kb1 * 2)) ^ ((d1 & 7) << 4)));
                oacc1 = MFMA32(t1.v, vf, oacc1);
            }
        }
    }
    if (hi == 0) lsh[w * 32 + l31] = 1.0f / lden;
    float li[16];
    #pragma unroll
    for (int r = 0; r < 16; ++r)
        li[r] = lsh[w * 32 + ((r & 3) + 8 * (r >> 2) + 4 * hi)];
    #pragma unroll
    for (int r = 0; r < 16; ++r) {
        int crow = (r & 3) + 8 * (r >> 2) + 4 * hi;
        size_t token = (size_t)b * 1024 + qb + w * 32 + crow;
        outbf[token * 1024 + hh * 64 + l31]      = f2bf(oacc0[r] * li[r]);
        outbf[token * 1024 + hh * 64 + 32 + l31] = f2bf(oacc1[r] * li[r]);
    }
}

extern "C" void kernel_launch(void* const* d_in, const int* in_sizes, int n_in,
                              void* d_out, int out_size, void* d_ws, size_t ws_size,
                              hipStream_t stream) {
    const float* x            = (const float*)d_in[0];
    const float* neuron_emb   = (const float*)d_in[1];
    const float* proj_attn_k  = (const float*)d_in[2];
    const float* proj_attn_b  = (const float*)d_in[3];
    const float* tau_attn_k   = (const float*)d_in[4];
    const float* tau_attn_b   = (const float*)d_in[5];
    const float* proj_know_k  = (const float*)d_in[6];
    const float* proj_know_b  = (const float*)d_in[7];
    const float* tau_know_k   = (const float*)d_in[8];
    const float* tau_know_b   = (const float*)d_in[9];
    const float* cluster_qk   = (const float*)d_in[10];
    const float* cluster_v    = (const float*)d_in[11];
    const float* cluster_know = (const float*)d_in[12];
    const float* qk_neurons   = (const float*)d_in[13];
    const float* v_neurons    = (const float*)d_in[14];
    const float* know_neurons = (const float*)d_in[15];
    const float* expand_O     = (const float*)d_in[16];
    const float* ln1_s        = (const float*)d_in[17];
    const float* ln1_b        = (const float*)d_in[18];
    const float* ln2_s        = (const float*)d_in[19];
    const float* ln2_b        = (const float*)d_in[20];
    float* out = (float*)d_out;

    char* wsb = (char*)d_ws;
    size_t off = 0;
    auto alloc = [&](size_t bytes) -> void* {
        void* p = wsb + off;
        off = (off + bytes + 255) & ~(size_t)255;
        return p;
    };
    u16*   emb16    = (u16*)alloc((size_t)16384 * 128 * 2);
    float* ceT      = (float*)alloc((size_t)3 * 128 * 64 * 4);
    u16*   nbf      = (u16*)alloc((size_t)16384 * 1024 * 2);
    float* h1       = (float*)alloc((size_t)NTOK * 1024 * 4);
    u16*   h1bf     = (u16*)alloc((size_t)NTOK * 1024 * 2);
    float* h_all    = (float*)alloc((size_t)NTOK * 384 * 4);
    float* tau_all  = (float*)alloc((size_t)NTOK * 3 * 4);
    float* h_know   = (float*)alloc((size_t)NTOK * 128 * 4);
    float* tau_kn   = (float*)alloc((size_t)NTOK * 4);
    int*   gidx     = (int*)alloc((size_t)4 * NTOK * CAP * 4);
    float* gvalp    = (float*)alloc((size_t)4 * NTOK * CAP * 4);
    int*   gcnt     = (int*)alloc((size_t)4 * NTOK * 4);
    u16*   qkv      = (u16*)alloc((size_t)3 * NTOK * 1024 * 2);
    u16*   projA_t  = (u16*)alloc((size_t)384 * 1024 * 2);
    u16*   know_t   = (u16*)alloc((size_t)128 * 1024 * 2);
    u16*   exp_t    = (u16*)alloc((size_t)1024 * 1024 * 2);
    float* cprob    = (float*)alloc((size_t)4 * NTOK * 64 * 4);
    float* partials = (float*)alloc((size_t)4 * 64 * 8192 * 4);
    float* cpart2   = (float*)alloc((size_t)4 * 64 * 64 * 4);

    u16* Qbuf = qkv;
    u16* Kbuf = qkv + (size_t)NTOK * 1024;
    u16* Vbuf = qkv + (size_t)2 * NTOK * 1024;
    u16* attn_bf = h1bf;

    hipMemsetAsync(out + (size_t)NTOK * 1024, 0, 4, stream);

    norm_rows_kernel<<<16384 / 4, 256, 0, stream>>>(neuron_emb, emb16, nullptr, 16384);
    norm_rows_kernel<<<16, 256, 0, stream>>>(cluster_qk, nullptr, ceT, 64);
    norm_rows_kernel<<<16, 256, 0, stream>>>(cluster_v, nullptr, ceT + 128 * 64, 64);
    norm_rows_kernel<<<16, 256, 0, stream>>>(cluster_know, nullptr, ceT + 2 * 128 * 64, 64);
    cast_bf16_kernel<<<4096, 256, 0, stream>>>(qk_neurons, nbf, 4096 * 1024);
    cast_bf16_kernel<<<4096, 256, 0, stream>>>(v_neurons, nbf + (size_t)4096 * 1024, 4096 * 1024);
    cast_bf16_kernel<<<8192, 256, 0, stream>>>(know_neurons, nbf + (size_t)8192 * 1024, 8192 * 1024);
    transpose_cast_kernel<<<dim3(6, 16), dim3(64, 4), 0, stream>>>(proj_attn_k, projA_t, 384, 1024);
    transpose_cast_kernel<<<dim3(2, 16), dim3(64, 4), 0, stream>>>(proj_know_k, know_t, 128, 1024);
    transpose_cast_kernel<<<dim3(16, 16), dim3(64, 4), 0, stream>>>(expand_O, exp_t, 1024, 1024);

    ln_kernel<<<NTOK, 256, 0, stream>>>(x, ln1_s, ln1_b, h1, h1bf);
    gemm_mfma_kernel<<<dim3(3, 32), 256, 0, stream>>>(h1bf, projA_t, proj_attn_b, nullptr, h_all, 384, 1024);
    vecproj_kernel<<<NTOK, 64, 0, stream>>>(h1, tau_attn_k, tau_attn_b, tau_all, 3);

    gate_wave_kernel<512, 6><<<dim3(1024, 3), 256, 0, stream>>>(
        h_all, 384, tau_all, 3, emb16, ceT, cprob, gidx, gvalp, gcnt);

    sense_emit_kernel<<<NTOK, 256, 0, stream>>>(h1, gidx, gvalp, gcnt, nbf, Qbuf, nullptr);
    sense_emit_kernel<<<NTOK, 256, 0, stream>>>(h1, gidx + (size_t)NTOK * CAP, gvalp + (size_t)NTOK * CAP,
                                                gcnt + NTOK, nbf, Kbuf, nullptr);
    sense_emit_kernel<<<NTOK, 256, 0, stream>>>(h1, gidx + (size_t)2 * NTOK * CAP, gvalp + (size_t)2 * NTOK * CAP,
                                                gcnt + 2 * NTOK, nbf + (size_t)4096 * 1024, Vbuf, nullptr);

    attn_kernel<<<dim3(8, 64), 256, 0, stream>>>(Qbuf, Kbuf, Vbuf, attn_bf);
    gemm_mfma_kernel<<<dim3(8, 32), 256, 0, stream>>>(attn_bf, exp_t, nullptr, x, out, 1024, 1024);

    ln_kernel<<<NTOK, 256, 0, stream>>>(out, ln2_s, ln2_b, h1, h1bf);
    gemm_mfma_kernel<<<dim3(1, 32), 256, 0, stream>>>(h1bf, know_t, proj_know_b, nullptr, h_know, 128, 1024);
    vecproj_kernel<<<NTOK, 64, 0, stream>>>(h1, tau_know_k, tau_know_b, tau_kn, 1);
    gate_wave_kernel<1024, 7><<<dim3(1024, 1), 256, 0, stream>>>(
        h_know, 128, tau_kn, 1, emb16 + (size_t)8192 * 128, ceT + 2 * 128 * 64,
        cprob + (size_t)3 * NTOK * 64,
        gidx + (size_t)3 * NTOK * CAP, gvalp + (size_t)3 * NTOK * CAP, gcnt + 3 * NTOK);
    sense_emit_kernel<<<NTOK, 256, 0, stream>>>(h1, gidx + (size_t)3 * NTOK * CAP, gvalp + (size_t)3 * NTOK * CAP,
                                                gcnt + 3 * NTOK, nbf + (size_t)8192 * 1024, nullptr, out);

    nfreq_partial_kernel<<<dim3(64, 4), 256, 0, stream>>>(gidx, gvalp, gcnt, cprob, partials, cpart2);
    aux2_kernel<<<84, 256, 0, stream>>>(partials, cpart2, out + (size_t)NTOK * 1024);
}